// Round 1
// baseline (5496.432 us; speedup 1.0000x reference)
//
#include <hip/hip_runtime.h>
#include <hip/hip_bf16.h>

#define TT 512
#define BB 64
#define EE 512
#define HH 1024

typedef __attribute__((ext_vector_type(8))) short short8;
typedef __attribute__((ext_vector_type(4))) float f32x4;

// workspace layout (bytes, 256-aligned)
//  X      : [T][B][E] bf16            = 33,554,432
//  Wt     : [256 ct][48 kk][512] bf16 = 12,582,912   (MFMA B-frag order)
//  hbuf   : [2][B][H] bf16            =    262,144
//  flags  : [T][256] int              =    524,288
#define WS_X     0
#define WS_WT    33554432
#define WS_HBUF  46137344
#define WS_FLAGS 46399488

static __device__ __forceinline__ unsigned short f2bf(float x) {
    unsigned int u = __float_as_uint(x);
    unsigned int r = (u + 0x7fffu + ((u >> 16) & 1u)) >> 16;
    return (unsigned short)r;
}

// ---------------- embedding gather -> bf16 X[t][b][e] ----------------
__global__ void embed_k(const int* __restrict__ src, const float* __restrict__ emb,
                        unsigned short* __restrict__ X) {
    int idx  = blockIdx.x * 256 + threadIdx.x;   // one float4 per thread
    int base = idx * 4;                          // = t*32768 + b*512 + e
    int t = base >> 15;
    int r = base & 32767;
    int b = r >> 9;
    int e = r & 511;
    int v = src[b * TT + t];
    float4 f = *(const float4*)(emb + (size_t)v * EE + e);
    ushort4 s;
    s.x = f2bf(f.x); s.y = f2bf(f.y); s.z = f2bf(f.z); s.w = f2bf(f.w);
    *(ushort4*)(X + base) = s;
}

// ------- weight transpose/convert into MFMA B-fragment order -------
// Wt[((ct*48+kk)*64+lane)*8+j] = Wcomb[k = kk*32+(lane>>4)*8+j][col = ct*16+(lane&15)]
__global__ void wprep_k(const float* __restrict__ Wih, const float* __restrict__ Whh,
                        unsigned short* __restrict__ Wt) {
    const int bid = blockIdx.x;          // = ct*48 + kk
    const int kk  = bid % 48;
    const int ct  = bid / 48;
    const int tid = threadIdx.x;
    const int k0 = kk * 32, c0 = ct * 16;
    __shared__ float tile[32][17];
    for (int e = tid; e < 512; e += 256) {
        int kr = e >> 4, cc = e & 15;
        int k = k0 + kr;
        float v = (k < EE) ? Wih[(size_t)k * 4096 + c0 + cc]
                           : Whh[(size_t)(k - EE) * 4096 + c0 + cc];
        tile[kr][cc] = v;
    }
    __syncthreads();
    for (int e = tid; e < 512; e += 256) {
        int lane = e >> 3, j = e & 7;
        float v = tile[(lane >> 4) * 8 + j][lane & 15];
        Wt[(size_t)bid * 512 + e] = f2bf(v);
    }
}

// ---------------- persistent recurrent kernel ----------------
// 256 WGs = 4 row-groups (16 batch rows) x 64 col-groups (16 hidden units = 64 cols).
// Weights resident in VGPRs: wave w holds kk = 4i+w (i=0..11) x 4 gate tiles = 192 VGPRs.
__global__ __launch_bounds__(256, 1) void lstm_k(
    const unsigned short* __restrict__ X,
    const unsigned short* __restrict__ Wt,
    const float* __restrict__ bias,
    unsigned short* __restrict__ hbuf,
    int* __restrict__ flags,
    float* __restrict__ out)
{
    const int g        = blockIdx.x;
    const int cg       = g & 63;
    const int rg       = g >> 6;
    const int row_base = rg * 16;
    const int ubase    = cg * 16;
    const int tid  = threadIdx.x;
    const int wave = tid >> 6;
    const int lane = tid & 63;
    const int lrow = lane & 15;
    const int quad = lane >> 4;

    __shared__ float zred[4][4][16][17];   // [wave][gate][m-row][n-col]
    __shared__ float sbias[64];

    if (tid < 64) sbias[tid] = bias[(tid >> 4) * HH + ubase + (tid & 15)];

    // resident weight fragments
    short8 wr[12][4];
#pragma unroll
    for (int i = 0; i < 12; ++i) {
        const int kk = i * 4 + wave;
#pragma unroll
        for (int g4 = 0; g4 < 4; ++g4) {
            const int ct = g4 * 64 + cg;
            wr[i][g4] = *(const short8*)(Wt + ((size_t)(ct * 48 + kk)) * 512 + lane * 8);
        }
    }

    // per-thread persistent cell state: thread owns (row = tid>>4, u = tid&15)
    const int erow = tid >> 4, eu = tid & 15;
    float creg = 0.f;
    __syncthreads();

    for (int t = 0; t < TT; ++t) {
        f32x4 acc0 = {0.f,0.f,0.f,0.f}, acc1 = {0.f,0.f,0.f,0.f};
        f32x4 acc2 = {0.f,0.f,0.f,0.f}, acc3 = {0.f,0.f,0.f,0.f};

        // ---- x-part (no recurrent dependency): kk = 0..15 ----
        const unsigned short* xp = X + ((size_t)(t * BB) + row_base + lrow) * EE + quad * 8;
#pragma unroll
        for (int i = 0; i < 4; ++i) {
            const int kk = i * 4 + wave;
            short8 a = *(const short8*)(xp + kk * 32);
            acc0 = __builtin_amdgcn_mfma_f32_16x16x32_bf16(a, wr[i][0], acc0, 0, 0, 0);
            acc1 = __builtin_amdgcn_mfma_f32_16x16x32_bf16(a, wr[i][1], acc1, 0, 0, 0);
            acc2 = __builtin_amdgcn_mfma_f32_16x16x32_bf16(a, wr[i][2], acc2, 0, 0, 0);
            acc3 = __builtin_amdgcn_mfma_f32_16x16x32_bf16(a, wr[i][3], acc3, 0, 0, 0);
        }

        // ---- wait for h(t-1) from our row-group's 64 WGs ----
        if (t > 0) {
            if (tid < 64) {
                const int fidx = (t - 1) * 256 + rg * 64 + tid;
                while (__hip_atomic_load(&flags[fidx], __ATOMIC_ACQUIRE,
                                         __HIP_MEMORY_SCOPE_AGENT) == 0) {
                    __builtin_amdgcn_s_sleep(1);
                }
            }
            __syncthreads();
        }

        // ---- h-part: kk = 16..47 ----
        const unsigned short* hp =
            hbuf + ((size_t)(((t & 1) ^ 1) * BB) + row_base + lrow) * HH + quad * 8;
#pragma unroll
        for (int i = 4; i < 12; ++i) {
            const int kk = i * 4 + wave;
            short8 a = *(const short8*)(hp + (kk * 32 - 512));
            acc0 = __builtin_amdgcn_mfma_f32_16x16x32_bf16(a, wr[i][0], acc0, 0, 0, 0);
            acc1 = __builtin_amdgcn_mfma_f32_16x16x32_bf16(a, wr[i][1], acc1, 0, 0, 0);
            acc2 = __builtin_amdgcn_mfma_f32_16x16x32_bf16(a, wr[i][2], acc2, 0, 0, 0);
            acc3 = __builtin_amdgcn_mfma_f32_16x16x32_bf16(a, wr[i][3], acc3, 0, 0, 0);
        }

        // ---- cross-wave K reduction via LDS ----
#pragma unroll
        for (int r = 0; r < 4; ++r) {
            zred[wave][0][quad * 4 + r][lrow] = acc0[r];
            zred[wave][1][quad * 4 + r][lrow] = acc1[r];
            zred[wave][2][quad * 4 + r][lrow] = acc2[r];
            zred[wave][3][quad * 4 + r][lrow] = acc3[r];
        }
        __syncthreads();

        // ---- gates / cell update: one (row,unit) per thread ----
        {
            float zi = zred[0][0][erow][eu] + zred[1][0][erow][eu]
                     + zred[2][0][erow][eu] + zred[3][0][erow][eu] + sbias[eu];
            float zf = zred[0][1][erow][eu] + zred[1][1][erow][eu]
                     + zred[2][1][erow][eu] + zred[3][1][erow][eu] + sbias[16 + eu];
            float zg = zred[0][2][erow][eu] + zred[1][2][erow][eu]
                     + zred[2][2][erow][eu] + zred[3][2][erow][eu] + sbias[32 + eu];
            float zo = zred[0][3][erow][eu] + zred[1][3][erow][eu]
                     + zred[2][3][erow][eu] + zred[3][3][erow][eu] + sbias[48 + eu];
            float iv = 1.f / (1.f + __expf(-zi));
            float fv = 1.f / (1.f + __expf(-zf));
            float gv = 1.f - 2.f / (__expf(2.f * zg) + 1.f);
            float ov = 1.f / (1.f + __expf(-zo));
            float c  = fv * creg + iv * gv;
            creg = c;
            float th = 1.f - 2.f / (__expf(2.f * c) + 1.f);
            float h  = ov * th;
            hbuf[((size_t)(t & 1) * BB + row_base + erow) * HH + ubase + eu] = f2bf(h);
            if (t == TT - 1) {
                out[(row_base + erow) * HH + ubase + eu] = h;             // h_T
                out[BB * HH + (row_base + erow) * HH + ubase + eu] = c;   // c_T
            }
        }
        __syncthreads();   // drains all waves' stores (vmcnt) before release

        if (tid == 0) {
            __hip_atomic_store(&flags[t * 256 + rg * 64 + cg], 1,
                               __ATOMIC_RELEASE, __HIP_MEMORY_SCOPE_AGENT);
        }
    }
}

extern "C" void kernel_launch(void* const* d_in, const int* in_sizes, int n_in,
                              void* d_out, int out_size, void* d_ws, size_t ws_size,
                              hipStream_t stream) {
    const int*   src  = (const int*)d_in[0];
    const float* emb  = (const float*)d_in[1];
    const float* Wih  = (const float*)d_in[2];
    const float* Whh  = (const float*)d_in[3];
    const float* bias = (const float*)d_in[4];
    float* out = (float*)d_out;

    char* ws = (char*)d_ws;
    unsigned short* X     = (unsigned short*)(ws + WS_X);
    unsigned short* Wt    = (unsigned short*)(ws + WS_WT);
    unsigned short* hbuf  = (unsigned short*)(ws + WS_HBUF);
    int*            flags = (int*)(ws + WS_FLAGS);

    hipMemsetAsync(hbuf, 0, 2 * BB * HH * 2, stream);
    hipMemsetAsync(flags, 0, TT * 256 * 4, stream);
    embed_k<<<dim3(16384), dim3(256), 0, stream>>>(src, emb, X);
    wprep_k<<<dim3(12288), dim3(256), 0, stream>>>(Wih, Whh, Wt);
    lstm_k<<<dim3(256), dim3(256), 0, stream>>>(X, Wt, bias, hbuf, flags, out);
}

// Round 2
// 2063.718 us; speedup vs baseline: 2.6634x; 2.6634x over previous
//
#include <hip/hip_runtime.h>
#include <hip/hip_bf16.h>

#define TT 512
#define BB 64
#define EE 512
#define HH 1024

typedef __attribute__((ext_vector_type(8))) short short8;
typedef __attribute__((ext_vector_type(4))) float f32x4;

// workspace layout (bytes, 256-aligned)
//  X      : [T][B][E] bf16            = 33,554,432
//  Wt     : [256 ct][48 kk][512] bf16 = 12,582,912   (MFMA B-frag order)
//  hbuf   : [2][B][H] bf16            =    262,144
//  flags  : [T][256] int              =    524,288
#define WS_X     0
#define WS_WT    33554432
#define WS_HBUF  46137344
#define WS_FLAGS 46399488

static __device__ __forceinline__ unsigned short f2bf(float x) {
    unsigned int u = __float_as_uint(x);
    unsigned int r = (u + 0x7fffu + ((u >> 16) & 1u)) >> 16;
    return (unsigned short)r;
}

// relaxed agent-scope atomics: per-access sc1 coherence, NO buffer_inv/wbl2
static __device__ __forceinline__ int fl_ld(const int* p) {
    return __hip_atomic_load(p, __ATOMIC_RELAXED, __HIP_MEMORY_SCOPE_AGENT);
}
static __device__ __forceinline__ void fl_st(int* p, int v) {
    __hip_atomic_store(p, v, __ATOMIC_RELAXED, __HIP_MEMORY_SCOPE_AGENT);
}
static __device__ __forceinline__ void h_st(unsigned int* p, unsigned int v) {
    __hip_atomic_store(p, v, __ATOMIC_RELAXED, __HIP_MEMORY_SCOPE_AGENT);
}
static __device__ __forceinline__ short8 h_ld16(const unsigned long long* p) {
    union { short8 v; unsigned long long q[2]; } u;
    u.q[0] = __hip_atomic_load(p,     __ATOMIC_RELAXED, __HIP_MEMORY_SCOPE_AGENT);
    u.q[1] = __hip_atomic_load(p + 1, __ATOMIC_RELAXED, __HIP_MEMORY_SCOPE_AGENT);
    return u.v;
}

// ---------------- embedding gather -> bf16 X[t][b][e] ----------------
__global__ void embed_k(const int* __restrict__ src, const float* __restrict__ emb,
                        unsigned short* __restrict__ X) {
    int idx  = blockIdx.x * 256 + threadIdx.x;   // one float4 per thread
    int base = idx * 4;                          // = t*32768 + b*512 + e
    int t = base >> 15;
    int r = base & 32767;
    int b = r >> 9;
    int e = r & 511;
    int v = src[b * TT + t];
    float4 f = *(const float4*)(emb + (size_t)v * EE + e);
    ushort4 s;
    s.x = f2bf(f.x); s.y = f2bf(f.y); s.z = f2bf(f.z); s.w = f2bf(f.w);
    *(ushort4*)(X + base) = s;
}

// ------- weight transpose/convert into MFMA B-fragment order -------
__global__ void wprep_k(const float* __restrict__ Wih, const float* __restrict__ Whh,
                        unsigned short* __restrict__ Wt) {
    const int bid = blockIdx.x;          // = ct*48 + kk
    const int kk  = bid % 48;
    const int ct  = bid / 48;
    const int tid = threadIdx.x;
    const int k0 = kk * 32, c0 = ct * 16;
    __shared__ float tile[32][17];
    for (int e = tid; e < 512; e += 256) {
        int kr = e >> 4, cc = e & 15;
        int k = k0 + kr;
        float v = (k < EE) ? Wih[(size_t)k * 4096 + c0 + cc]
                           : Whh[(size_t)(k - EE) * 4096 + c0 + cc];
        tile[kr][cc] = v;
    }
    __syncthreads();
    for (int e = tid; e < 512; e += 256) {
        int lane = e >> 3, j = e & 7;
        float v = tile[(lane >> 4) * 8 + j][lane & 15];
        Wt[(size_t)bid * 512 + e] = f2bf(v);
    }
}

// ---------------- persistent recurrent kernel ----------------
// 256 WGs = 4 row-groups (16 batch rows) x 64 col-groups (16 hidden units).
// Weights resident in VGPR/AGPR: wave w holds kk = 4i+w (i=0..11) x 4 gate tiles.
__global__ __launch_bounds__(256, 1) void lstm_k(
    const unsigned short* __restrict__ X,
    const unsigned short* __restrict__ Wt,
    const float* __restrict__ bias,
    unsigned short* __restrict__ hbuf,
    int* __restrict__ flags,
    float* __restrict__ out)
{
    const int g        = blockIdx.x;
    const int cg       = g & 63;
    const int rg       = g >> 6;
    const int row_base = rg * 16;
    const int ubase    = cg * 16;
    const int tid  = threadIdx.x;
    const int wave = tid >> 6;
    const int lane = tid & 63;
    const int lrow = lane & 15;
    const int quad = lane >> 4;

    __shared__ float zred[4][4][16][17];      // [wave][gate][m-row][n-col]
    __shared__ float sbias[64];
    __shared__ unsigned short sh_h[16][16];   // staged h bf16 for packed stores

    if (tid < 64) sbias[tid] = bias[(tid >> 4) * HH + ubase + (tid & 15)];

    // resident weight fragments
    short8 wr[12][4];
#pragma unroll
    for (int i = 0; i < 12; ++i) {
        const int kk = i * 4 + wave;
#pragma unroll
        for (int g4 = 0; g4 < 4; ++g4) {
            const int ct = g4 * 64 + cg;
            wr[i][g4] = *(const short8*)(Wt + ((size_t)(ct * 48 + kk)) * 512 + lane * 8);
        }
    }

    // per-thread persistent cell state: thread owns (row = tid>>4, u = tid&15)
    const int erow = tid >> 4, eu = tid & 15;
    float creg = 0.f;
    __syncthreads();

    for (int t = 0; t < TT; ++t) {
        f32x4 acc0 = {0.f,0.f,0.f,0.f}, acc1 = {0.f,0.f,0.f,0.f};
        f32x4 acc2 = {0.f,0.f,0.f,0.f}, acc3 = {0.f,0.f,0.f,0.f};

        // ---- x-part (no recurrent dependency): kk = 0..15, cached loads ----
        const unsigned short* xp = X + ((size_t)(t * BB) + row_base + lrow) * EE + quad * 8;
#pragma unroll
        for (int i = 0; i < 4; ++i) {
            const int kk = i * 4 + wave;
            short8 a = *(const short8*)(xp + kk * 32);
            acc0 = __builtin_amdgcn_mfma_f32_16x16x32_bf16(a, wr[i][0], acc0, 0, 0, 0);
            acc1 = __builtin_amdgcn_mfma_f32_16x16x32_bf16(a, wr[i][1], acc1, 0, 0, 0);
            acc2 = __builtin_amdgcn_mfma_f32_16x16x32_bf16(a, wr[i][2], acc2, 0, 0, 0);
            acc3 = __builtin_amdgcn_mfma_f32_16x16x32_bf16(a, wr[i][3], acc3, 0, 0, 0);
        }

        // ---- wait for h(t-1) flags (relaxed poll, no cache maintenance) ----
        if (t > 0) {
            if (tid < 64) {
                const int fidx = (t - 1) * 256 + rg * 64 + tid;
                while (fl_ld(&flags[fidx]) == 0) {
                    __builtin_amdgcn_s_sleep(1);
                }
            }
            __syncthreads();
        }

        // ---- h-part: kk = 16..47, sc1 loads straight from LLC ----
        const unsigned long long* hq = (const unsigned long long*)hbuf
            + ((size_t)(((t & 1) ^ 1) * BB) + row_base + lrow) * (HH / 4) + quad * 2;
        short8 ah[8];
#pragma unroll
        for (int i = 0; i < 8; ++i) {
            const int kk = (i + 4) * 4 + wave;          // 16..47
            ah[i] = h_ld16(hq + (kk * 8 - 128));
        }
#pragma unroll
        for (int i = 0; i < 8; ++i) {
            acc0 = __builtin_amdgcn_mfma_f32_16x16x32_bf16(ah[i], wr[i + 4][0], acc0, 0, 0, 0);
            acc1 = __builtin_amdgcn_mfma_f32_16x16x32_bf16(ah[i], wr[i + 4][1], acc1, 0, 0, 0);
            acc2 = __builtin_amdgcn_mfma_f32_16x16x32_bf16(ah[i], wr[i + 4][2], acc2, 0, 0, 0);
            acc3 = __builtin_amdgcn_mfma_f32_16x16x32_bf16(ah[i], wr[i + 4][3], acc3, 0, 0, 0);
        }

        // ---- cross-wave K reduction via LDS ----
#pragma unroll
        for (int r = 0; r < 4; ++r) {
            zred[wave][0][quad * 4 + r][lrow] = acc0[r];
            zred[wave][1][quad * 4 + r][lrow] = acc1[r];
            zred[wave][2][quad * 4 + r][lrow] = acc2[r];
            zred[wave][3][quad * 4 + r][lrow] = acc3[r];
        }
        __syncthreads();

        // ---- gates / cell update: one (row,unit) per thread ----
        {
            float zi = zred[0][0][erow][eu] + zred[1][0][erow][eu]
                     + zred[2][0][erow][eu] + zred[3][0][erow][eu] + sbias[eu];
            float zf = zred[0][1][erow][eu] + zred[1][1][erow][eu]
                     + zred[2][1][erow][eu] + zred[3][1][erow][eu] + sbias[16 + eu];
            float zg = zred[0][2][erow][eu] + zred[1][2][erow][eu]
                     + zred[2][2][erow][eu] + zred[3][2][erow][eu] + sbias[32 + eu];
            float zo = zred[0][3][erow][eu] + zred[1][3][erow][eu]
                     + zred[2][3][erow][eu] + zred[3][3][erow][eu] + sbias[48 + eu];
            float iv = 1.f / (1.f + __expf(-zi));
            float fv = 1.f / (1.f + __expf(-zf));
            float gv = 1.f - 2.f / (__expf(2.f * zg) + 1.f);
            float ov = 1.f / (1.f + __expf(-zo));
            float c  = fv * creg + iv * gv;
            creg = c;
            float th = 1.f - 2.f / (__expf(2.f * c) + 1.f);
            float h  = ov * th;
            sh_h[erow][eu] = f2bf(h);
            if (t == TT - 1) {
                out[(row_base + erow) * HH + ubase + eu] = h;             // h_T
                out[BB * HH + (row_base + erow) * HH + ubase + eu] = c;   // c_T
            }
        }
        __syncthreads();   // sh_h ready (also WAR-protects zred)

        // ---- packed write-through h stores (sc1, never dirty in L2) ----
        if (tid < 128) {
            const int r = tid >> 3, p = tid & 7;
            unsigned int v = (unsigned int)sh_h[r][2 * p]
                           | ((unsigned int)sh_h[r][2 * p + 1] << 16);
            unsigned int* hw = (unsigned int*)hbuf;
            size_t idx = ((size_t)(t & 1) * BB + row_base + r) * (HH / 2)
                       + (ubase >> 1) + p;
            h_st(hw + idx, v);
        }
        __syncthreads();   // each wave drains vmcnt(0) before s_barrier -> h visible

        if (tid == 0) {
            fl_st(&flags[t * 256 + rg * 64 + cg], 1);
        }
    }
}

extern "C" void kernel_launch(void* const* d_in, const int* in_sizes, int n_in,
                              void* d_out, int out_size, void* d_ws, size_t ws_size,
                              hipStream_t stream) {
    const int*   src  = (const int*)d_in[0];
    const float* emb  = (const float*)d_in[1];
    const float* Wih  = (const float*)d_in[2];
    const float* Whh  = (const float*)d_in[3];
    const float* bias = (const float*)d_in[4];
    float* out = (float*)d_out;

    char* ws = (char*)d_ws;
    unsigned short* X     = (unsigned short*)(ws + WS_X);
    unsigned short* Wt    = (unsigned short*)(ws + WS_WT);
    unsigned short* hbuf  = (unsigned short*)(ws + WS_HBUF);
    int*            flags = (int*)(ws + WS_FLAGS);

    hipMemsetAsync(hbuf, 0, 2 * BB * HH * 2, stream);
    hipMemsetAsync(flags, 0, TT * 256 * 4, stream);
    embed_k<<<dim3(16384), dim3(256), 0, stream>>>(src, emb, X);
    wprep_k<<<dim3(12288), dim3(256), 0, stream>>>(Wih, Whh, Wt);
    lstm_k<<<dim3(256), dim3(256), 0, stream>>>(X, Wt, bias, hbuf, flags, out);
}

// Round 5
// 2047.367 us; speedup vs baseline: 2.6846x; 1.0080x over previous
//
#include <hip/hip_runtime.h>
#include <hip/hip_bf16.h>

#define TT 512
#define BB 64
#define EE 512
#define HH 1024

typedef __attribute__((ext_vector_type(8))) short short8;
typedef __attribute__((ext_vector_type(4))) float f32x4;

// workspace layout (bytes)
//  X      : [T][B][E] bf16             = 33,554,432
//  Wt     : [256 ct][48 kk][512] bf16  = 12,582,912   (MFMA B-frag order)
//  hbuf   : [2][B][H] bf16             =    262,144
//  flags  : [T][4 rg][64 cg][4] int    =  2,097,152   (16B-strided flags)
//  probe  : [16] int                   =         64   (asm idiom diagnostic)
#define WS_X     0
#define WS_WT    33554432
#define WS_HBUF  46137344
#define WS_FLAGS 46399488
#define WS_PROBE 48496640

static __device__ __forceinline__ unsigned short f2bf(float x) {
    unsigned int u = __float_as_uint(x);
    unsigned int r = (u + 0x7fffu + ((u >> 16) & 1u)) >> 16;
    return (unsigned short)r;
}

// relaxed agent-scope atomics (proven R2 path): per-access coherence,
// no buffer_inv / buffer_wbl2 cache maintenance
static __device__ __forceinline__ int fl_ld(const int* p) {
    return __hip_atomic_load(p, __ATOMIC_RELAXED, __HIP_MEMORY_SCOPE_AGENT);
}
static __device__ __forceinline__ void fl_st(int* p, int v) {
    __hip_atomic_store(p, v, __ATOMIC_RELAXED, __HIP_MEMORY_SCOPE_AGENT);
}
static __device__ __forceinline__ void h_st(unsigned int* p, unsigned int v) {
    __hip_atomic_store(p, v, __ATOMIC_RELAXED, __HIP_MEMORY_SCOPE_AGENT);
}
static __device__ __forceinline__ short8 h_ld16(const unsigned long long* p) {
    union { short8 v; unsigned long long q[2]; } u;
    u.q[0] = __hip_atomic_load(p,     __ATOMIC_RELAXED, __HIP_MEMORY_SCOPE_AGENT);
    u.q[1] = __hip_atomic_load(p + 1, __ATOMIC_RELAXED, __HIP_MEMORY_SCOPE_AGENT);
    return u.v;
}

// ---------------- embedding gather -> bf16 X[t][b][e] ----------------
__global__ void embed_k(const int* __restrict__ src, const float* __restrict__ emb,
                        unsigned short* __restrict__ X) {
    int idx  = blockIdx.x * 256 + threadIdx.x;   // one float4 per thread
    int base = idx * 4;                          // = t*32768 + b*512 + e
    int t = base >> 15;
    int r = base & 32767;
    int b = r >> 9;
    int e = r & 511;
    int v = src[b * TT + t];
    float4 f = *(const float4*)(emb + (size_t)v * EE + e);
    ushort4 s;
    s.x = f2bf(f.x); s.y = f2bf(f.y); s.z = f2bf(f.z); s.w = f2bf(f.w);
    *(ushort4*)(X + base) = s;
}

// ------- weight transpose/convert into MFMA B-fragment order -------
// Wt[((ct*48+kk)*64+lane)*8+j] = Wcomb[k = kk*32+(lane>>4)*8+j][col = ct*16+(lane&15)]
__global__ void wprep_k(const float* __restrict__ Wih, const float* __restrict__ Whh,
                        unsigned short* __restrict__ Wt, int* __restrict__ probe) {
    const int bid = blockIdx.x;          // = ct*48 + kk
    const int kk  = bid % 48;
    const int ct  = bid / 48;
    const int tid = threadIdx.x;

    // ---- DIAGNOSTIC PROBE (harmless): test the 3 asm idioms that were new
    // in the crashed R3/R4 kernels. Result is written to a spare ws slot and
    // never read. If this round passes, the idioms compile+execute fine.
    if (bid == 0 && tid == 0) {
        int xcd;
        asm volatile("s_getreg_b32 %0, hwreg(HW_REG_XCC_ID)" : "=s"(xcd));
        int* pr = probe;
        asm volatile("global_store_dword %0, %1, off sc0"
                     :: "v"(pr), "v"(xcd) : "memory");
        int v;
        asm volatile("global_load_dword %0, %1, off sc0\n\ts_waitcnt vmcnt(0)"
                     : "=v"(v) : "v"(pr) : "memory");
        pr[1] = v;
    }

    const int k0 = kk * 32, c0 = ct * 16;
    __shared__ float tile[32][17];
    for (int e = tid; e < 512; e += 256) {
        int kr = e >> 4, cc = e & 15;
        int k = k0 + kr;
        float v = (k < EE) ? Wih[(size_t)k * 4096 + c0 + cc]
                           : Whh[(size_t)(k - EE) * 4096 + c0 + cc];
        tile[kr][cc] = v;
    }
    __syncthreads();
    for (int e = tid; e < 512; e += 256) {
        int lane = e >> 3, j = e & 7;
        float v = tile[(lane >> 4) * 8 + j][lane & 15];
        Wt[(size_t)bid * 512 + e] = f2bf(v);
    }
}

// ---------------- persistent recurrent kernel ----------------
// 256 WGs = 4 row-groups (16 batch rows) x 64 col-groups (16 hidden units).
// Weights resident in VGPR/AGPR: wave w holds kk = 4i+w (i=0..11) x 4 gates.
__global__ __launch_bounds__(256, 1) void lstm_k(
    const unsigned short* __restrict__ X,
    const unsigned short* __restrict__ Wt,
    const float* __restrict__ bias,
    unsigned short* __restrict__ hbuf,
    int* __restrict__ flags,
    float* __restrict__ out)
{
    const int g        = blockIdx.x;
    const int cg       = g & 63;
    const int rg       = g >> 6;
    const int row_base = rg * 16;
    const int ubase    = cg * 16;
    const int tid  = threadIdx.x;
    const int wave = tid >> 6;
    const int lane = tid & 63;
    const int lrow = lane & 15;
    const int quad = lane >> 4;

    __shared__ float zred[4][4][16][17];      // [wave][gate][m-row][n-col]
    __shared__ float sbias[64];

    if (tid < 64) sbias[tid] = bias[(tid >> 4) * HH + ubase + (tid & 15)];

    // resident weight fragments
    short8 wr[12][4];
#pragma unroll
    for (int i = 0; i < 12; ++i) {
        const int kk = i * 4 + wave;
#pragma unroll
        for (int g4 = 0; g4 < 4; ++g4) {
            const int ct = g4 * 64 + cg;
            wr[i][g4] = *(const short8*)(Wt + ((size_t)(ct * 48 + kk)) * 512 + lane * 8);
        }
    }

    // per-thread persistent cell state: thread owns (row = tid>>4, u = tid&15)
    const int erow = tid >> 4, eu = tid & 15;
    float creg = 0.f;
    __syncthreads();

    for (int t = 0; t < TT; ++t) {
        f32x4 acc0 = {0.f,0.f,0.f,0.f}, acc1 = {0.f,0.f,0.f,0.f};
        f32x4 acc2 = {0.f,0.f,0.f,0.f}, acc3 = {0.f,0.f,0.f,0.f};

        // ---- x-part (no recurrent dependency): kk = 0..15, cached loads ----
        const unsigned short* xp = X + ((size_t)(t * BB) + row_base + lrow) * EE + quad * 8;
#pragma unroll
        for (int i = 0; i < 4; ++i) {
            const int kk = i * 4 + wave;
            short8 a = *(const short8*)(xp + kk * 32);
            acc0 = __builtin_amdgcn_mfma_f32_16x16x32_bf16(a, wr[i][0], acc0, 0, 0, 0);
            acc1 = __builtin_amdgcn_mfma_f32_16x16x32_bf16(a, wr[i][1], acc1, 0, 0, 0);
            acc2 = __builtin_amdgcn_mfma_f32_16x16x32_bf16(a, wr[i][2], acc2, 0, 0, 0);
            acc3 = __builtin_amdgcn_mfma_f32_16x16x32_bf16(a, wr[i][3], acc3, 0, 0, 0);
        }

        // ---- wait for h(t-1) flags: wave 0, one 16B-strided flag per lane ----
        if (t > 0) {
            if (tid < 64) {
                const int* fp = &flags[(((t - 1) * 4 + rg) * 64 + tid) * 4];
                while (fl_ld(fp) == 0) { }
            }
            __syncthreads();
        }

        // ---- h-part: kk = 16..47, LLC-coherent loads ----
        const unsigned long long* hq = (const unsigned long long*)hbuf
            + ((size_t)(((t & 1) ^ 1) * BB) + row_base + lrow) * (HH / 4) + quad * 2;
        short8 ah[8];
#pragma unroll
        for (int i = 0; i < 8; ++i) {
            const int kk = (i + 4) * 4 + wave;          // 16..47
            ah[i] = h_ld16(hq + (kk * 8 - 128));
        }
#pragma unroll
        for (int i = 0; i < 8; ++i) {
            acc0 = __builtin_amdgcn_mfma_f32_16x16x32_bf16(ah[i], wr[i + 4][0], acc0, 0, 0, 0);
            acc1 = __builtin_amdgcn_mfma_f32_16x16x32_bf16(ah[i], wr[i + 4][1], acc1, 0, 0, 0);
            acc2 = __builtin_amdgcn_mfma_f32_16x16x32_bf16(ah[i], wr[i + 4][2], acc2, 0, 0, 0);
            acc3 = __builtin_amdgcn_mfma_f32_16x16x32_bf16(ah[i], wr[i + 4][3], acc3, 0, 0, 0);
        }

        // ---- cross-wave K reduction via LDS ----
#pragma unroll
        for (int r = 0; r < 4; ++r) {
            zred[wave][0][quad * 4 + r][lrow] = acc0[r];
            zred[wave][1][quad * 4 + r][lrow] = acc1[r];
            zred[wave][2][quad * 4 + r][lrow] = acc2[r];
            zred[wave][3][quad * 4 + r][lrow] = acc3[r];
        }
        __syncthreads();

        // ---- gates / cell update + direct packed h store ----
        {
            float zi = zred[0][0][erow][eu] + zred[1][0][erow][eu]
                     + zred[2][0][erow][eu] + zred[3][0][erow][eu] + sbias[eu];
            float zf = zred[0][1][erow][eu] + zred[1][1][erow][eu]
                     + zred[2][1][erow][eu] + zred[3][1][erow][eu] + sbias[16 + eu];
            float zg = zred[0][2][erow][eu] + zred[1][2][erow][eu]
                     + zred[2][2][erow][eu] + zred[3][2][erow][eu] + sbias[32 + eu];
            float zo = zred[0][3][erow][eu] + zred[1][3][erow][eu]
                     + zred[2][3][erow][eu] + zred[3][3][erow][eu] + sbias[48 + eu];
            float iv = 1.f / (1.f + __expf(-zi));
            float fv = 1.f / (1.f + __expf(-zf));
            float gv = 1.f - 2.f / (__expf(2.f * zg) + 1.f);
            float ov = 1.f / (1.f + __expf(-zo));
            float c  = fv * creg + iv * gv;
            creg = c;
            float th = 1.f - 2.f / (__expf(2.f * c) + 1.f);
            float h  = ov * th;

            // pack pairs of adjacent units via shfl (lanes eu, eu^1 same wave)
            float hp = __shfl_xor(h, 1);
            if ((eu & 1) == 0) {
                unsigned int v = (unsigned int)f2bf(h)
                               | ((unsigned int)f2bf(hp) << 16);
                unsigned int* hw = (unsigned int*)hbuf;
                h_st(hw + ((size_t)(t & 1) * BB + row_base + erow) * (HH / 2)
                        + (ubase >> 1) + (eu >> 1), v);
            }
            if (t == TT - 1) {
                out[(row_base + erow) * HH + ubase + eu] = h;             // h_T
                out[BB * HH + (row_base + erow) * HH + ubase + eu] = c;   // c_T
            }
        }
        __syncthreads();   // drains h-stores (vmcnt) + WAR-protects zred

        if (tid == 0) {
            fl_st(&flags[((t * 4 + rg) * 64 + cg) * 4], 1);
        }
    }
}

extern "C" void kernel_launch(void* const* d_in, const int* in_sizes, int n_in,
                              void* d_out, int out_size, void* d_ws, size_t ws_size,
                              hipStream_t stream) {
    const int*   src  = (const int*)d_in[0];
    const float* emb  = (const float*)d_in[1];
    const float* Wih  = (const float*)d_in[2];
    const float* Whh  = (const float*)d_in[3];
    const float* bias = (const float*)d_in[4];
    float* out = (float*)d_out;

    char* ws = (char*)d_ws;
    unsigned short* X     = (unsigned short*)(ws + WS_X);
    unsigned short* Wt    = (unsigned short*)(ws + WS_WT);
    unsigned short* hbuf  = (unsigned short*)(ws + WS_HBUF);
    int*            flags = (int*)(ws + WS_FLAGS);
    int*            probe = (int*)(ws + WS_PROBE);

    hipMemsetAsync(hbuf, 0, 2 * BB * HH * 2, stream);
    hipMemsetAsync(flags, 0, TT * 4 * 64 * 4 * 4, stream);
    embed_k<<<dim3(16384), dim3(256), 0, stream>>>(src, emb, X);
    wprep_k<<<dim3(12288), dim3(256), 0, stream>>>(Wih, Whh, Wt, probe);
    lstm_k<<<dim3(256), dim3(256), 0, stream>>>(X, Wt, bias, hbuf, flags, out);
}